// Round 4
// baseline (230.774 us; speedup 1.0000x reference)
//
#include <hip/hip_runtime.h>
#include <stdint.h>

typedef _Float16 f16x2 __attribute__((ext_vector_type(2)));
typedef _Float16 f16x8 __attribute__((ext_vector_type(8)));
typedef float f32x4 __attribute__((ext_vector_type(4)));

static __device__ __forceinline__ uint32_t perm(uint32_t hi, uint32_t lo, uint32_t sel) {
    // bytes 0-3 from `lo`, bytes 4-7 from `hi` (matches __byte_perm(x,y,s) == perm(y,x,s))
    return __builtin_amdgcn_perm(hi, lo, sel);
}
static __device__ __forceinline__ f16x2 bch2(uint32_t u) { union { uint32_t x; f16x2 h; } c; c.x = u; return c.h; }
static __device__ __forceinline__ uint32_t bcu(f16x2 h) { union { uint32_t x; f16x2 h; } c; c.h = h; return c.x; }
// cvt_pkrtz returns __fp16x2 (distinct from _Float16x2) — bit-cast through its own type
static __device__ __forceinline__ uint32_t pkrtz(float a, float b) {
    auto r = __builtin_amdgcn_cvt_pkrtz(a, b);
    union { decltype(r) h; uint32_t u; } c; c.h = r; return c.u;
}

#define NTOT 8192
#define KTOT 8192
#define SPLITS 16
#define KCHUNK 512   // K per block
#define BN 256       // N per block (4 waves x 64)

// out[m][n] = bias[n]  (64 x 8192 f32, as float4)
__global__ __launch_bounds__(256, 2) void nvfp4_init_out(const float* __restrict__ bias,
                                                         float* __restrict__ out) {
    int i = blockIdx.x * 256 + threadIdx.x;      // 131072 float4s
    ((f32x4*)out)[i] = ((const f32x4*)bias)[i & 2047];
}

__global__ __launch_bounds__(256, 2) void nvfp4_gemm(const float* __restrict__ x,
                                                     const int* __restrict__ wp,
                                                     const float* __restrict__ ws,
                                                     const float* __restrict__ gs,
                                                     float* __restrict__ out) {
    // LDS: x half-tile [64][256] f16, XOR-swizzled (32 KiB) + scales [256][33] f32 (33 KiB)
    __shared__ __align__(16) uint8_t xl[64 * 256 * 2];
    __shared__ float sl[256 * 33];

    const int tid = threadIdx.x;
    const int nb = blockIdx.x & 31;     // n-block 0..31
    const int ksp = blockIdx.x >> 5;    // k-split 0..15
    const int nbase = nb * BN;
    const int kc0 = ksp * KCHUNK;

    // ---- stage scales (x inv_g) into padded LDS ----
    {
        float g = gs[0];
        float inv_g = (g != 0.0f) ? (1.0f / g) : 1.0f;
        int r = tid >> 3;             // 0..31
        int c = (tid & 7) * 4;        // 0..28
        for (int p = 0; p < 8; ++p) {
            int row = r + p * 32;
            f32x4 v = *(const f32x4*)(ws + (size_t)(nbase + row) * 512 + (kc0 >> 4) + c);
            sl[row * 33 + c + 0] = v.x * inv_g;
            sl[row * 33 + c + 1] = v.y * inv_g;
            sl[row * 33 + c + 2] = v.z * inv_g;
            sl[row * 33 + c + 3] = v.w * inv_g;
        }
    }

    const int lane = tid & 63;
    const int wid = tid >> 6;     // 0..3
    const int l15 = lane & 15;
    const int grp = lane >> 4;    // 0..3

    f32x4 acc[4][4];
    #pragma unroll
    for (int a = 0; a < 4; ++a)
        #pragma unroll
        for (int b = 0; b < 4; ++b)
            acc[a][b] = f32x4{0.f, 0.f, 0.f, 0.f};

    const uint32_t TH = 0x46444240u, TL = 0x3E3C3800u;  // f16 high-byte tables for e2m1 mags

    for (int half = 0; half < 2; ++half) {
        __syncthreads();   // xl reuse guard (also orders scale staging before first sl read)
        // ---- stage x half-tile: rows 0..63, k in [kc0+half*256, +256) as swizzled f16 ----
        {
            int a = tid >> 5;          // 0..7
            int b = tid & 31;          // 0..31
            int cb = b * 8;            // f16 col within half-tile
            const float* xp = x + (size_t)a * KTOT + kc0 + half * 256 + cb;
            #pragma unroll
            for (int j = 0; j < 8; ++j) {
                int row = a + j * 8;
                f32x4 v0 = *(const f32x4*)(xp + (size_t)j * 8 * KTOT);
                f32x4 v1 = *(const f32x4*)(xp + (size_t)j * 8 * KTOT + 4);
                uint4 d;
                d.x = pkrtz(v0.x, v0.y);
                d.y = pkrtz(v0.z, v0.w);
                d.z = pkrtz(v1.x, v1.y);
                d.w = pkrtz(v1.z, v1.w);
                uint32_t addr = ((uint32_t)(row * 512 + cb * 2)) ^ ((row & 7) << 4);
                *(uint4*)(xl + addr) = d;
            }
        }
        __syncthreads();

        // ---- 8 k-steps of 32 ----
        #pragma unroll 2
        for (int kk = 0; kk < 8; ++kk) {
            const int kg = kc0 + half * 256 + kk * 32;      // global k base of step
            // W packed loads: 4 n-sub-strips, 16B/lane (8 weights)
            int4 w4[4];
            float sf[4];
            const int scol = half * 16 + kk * 2 + (grp >> 1);
            #pragma unroll
            for (int ss = 0; ss < 4; ++ss) {
                int wrow = nbase + wid * 64 + ss * 16 + l15;
                w4[ss] = *(const int4*)(wp + (size_t)wrow * 4096 + (kg >> 1) + grp * 4);
                sf[ss] = sl[(wid * 64 + ss * 16 + l15) * 33 + scol];
            }
            // A fragments from swizzled LDS
            f16x8 af[4];
            #pragma unroll
            for (int mt = 0; mt < 4; ++mt) {
                int row = mt * 16 + l15;
                uint32_t addr = ((uint32_t)(row * 512 + (kk * 32 + grp * 8) * 2)) ^ ((row & 7) << 4);
                af[mt] = *(const f16x8*)(xl + addr);
            }
            #pragma unroll
            for (int ss = 0; ss < 4; ++ss) {
                f16x2 s2 = bch2(pkrtz(sf[ss], sf[ss]));
                uint32_t b = (uint32_t)(w4[ss].x & 0xff) | ((uint32_t)(w4[ss].y & 0xff) << 8) |
                             ((uint32_t)(w4[ss].z & 0xff) << 16) | ((uint32_t)w4[ss].w << 24);
                uint32_t sel_e = b & 0x07070707u;
                uint32_t sel_o = (b >> 4) & 0x07070707u;
                uint32_t he = perm(TH, TL, sel_e) | ((b & 0x08080808u) << 4);
                uint32_t ho = perm(TH, TL, sel_o) | (b & 0x80808080u);
                uint32_t d0 = perm(ho, he, 0x040C000Cu);
                uint32_t d1 = perm(ho, he, 0x050C010Cu);
                uint32_t d2 = perm(ho, he, 0x060C020Cu);
                uint32_t d3 = perm(ho, he, 0x070C030Cu);
                union { uint32_t u[4]; f16x8 h; } fr;
                fr.u[0] = bcu(bch2(d0) * s2);
                fr.u[1] = bcu(bch2(d1) * s2);
                fr.u[2] = bcu(bch2(d2) * s2);
                fr.u[3] = bcu(bch2(d3) * s2);
                #pragma unroll
                for (int mt = 0; mt < 4; ++mt)
                    acc[mt][ss] = __builtin_amdgcn_mfma_f32_16x16x32_f16(af[mt], fr.h, acc[mt][ss], 0, 0, 0);
            }
        }
    }

    // ---- epilogue: atomic-add partial tile into out ----
    #pragma unroll
    for (int mt = 0; mt < 4; ++mt)
        #pragma unroll
        for (int ss = 0; ss < 4; ++ss)
            #pragma unroll
            for (int q = 0; q < 4; ++q) {
                int row = mt * 16 + grp * 4 + q;
                int col = nbase + wid * 64 + ss * 16 + l15;
                unsafeAtomicAdd(out + (size_t)row * NTOT + col, acc[mt][ss][q]);
            }
}

extern "C" void kernel_launch(void* const* d_in, const int* in_sizes, int n_in,
                              void* d_out, int out_size, void* d_ws, size_t ws_size,
                              hipStream_t stream) {
    const float* x = (const float*)d_in[0];
    const int* wp = (const int*)d_in[1];
    const float* ws = (const float*)d_in[2];
    const float* gs = (const float*)d_in[3];
    const float* bias = (const float*)d_in[4];
    float* out = (float*)d_out;

    nvfp4_init_out<<<dim3(512), dim3(256), 0, stream>>>(bias, out);
    nvfp4_gemm<<<dim3(SPLITS * (NTOT / BN)), dim3(256), 0, stream>>>(x, wp, ws, gs, out);
}